// Round 6
// baseline (261.351 us; speedup 1.0000x reference)
//
#include <hip/hip_runtime.h>

#define NNODES 20000
#define BATCH  2
#define FEAT   256
#define OOUT   64
#define PBLK   200
#define MROWS  (BATCH * NNODES)   // 40000
#define MPAD   40064              // 626 * 64

typedef short  bhalf8 __attribute__((ext_vector_type(8)));   // 8 bf16 in 4 VGPRs
typedef float  floatx4 __attribute__((ext_vector_type(4)));
typedef float  floatx2 __attribute__((ext_vector_type(2)));

// ---------- bf16 helpers ----------
__device__ __forceinline__ float bf2f(unsigned short u) {
  return __uint_as_float(((unsigned int)u) << 16);
}
__device__ __forceinline__ unsigned short f2bf(float f) {  // round-to-nearest-even
  unsigned int u = __float_as_uint(f);
  return (unsigned short)((u + 0x7fffu + ((u >> 16) & 1u)) >> 16);
}

// ---------- fp8 e4m3 helpers (HW converts, RNE) ----------
__device__ __forceinline__ unsigned int pack4_fp8(float a, float b, float c, float d) {
  int p = __builtin_amdgcn_cvt_pk_fp8_f32(a, b, 0, false);   // bytes 0,1
  p = __builtin_amdgcn_cvt_pk_fp8_f32(c, d, p, true);        // bytes 2,3
  return (unsigned int)p;
}

// ---------- detect edge dtype + zero cnt/fill (single block) ----------
__global__ __launch_bounds__(256) void detect_zero_kernel(const int* __restrict__ raw,
                                                          int* __restrict__ flag,
                                                          int* __restrict__ cnt,
                                                          int* __restrict__ fill, int E) {
  for (int i = threadIdx.x; i < NNODES; i += 256) { cnt[i] = 0; fill[i] = 0; }
  __shared__ int any;
  if (threadIdx.x == 0) any = 0;
  __syncthreads();
  int nchk = E < 2048 ? E : 2048;
  for (int i = threadIdx.x; i < nchk; i += blockDim.x)
    if (raw[2 * i + 1] != 0) any = 1;   // int64 high words are 0 (values < 20000)
  __syncthreads();
  if (threadIdx.x == 0) *flag = any;    // 1 => int32 layout, 0 => int64 layout
}

// ---------- convert + degree count ----------
__global__ void convert_count_kernel(const int* __restrict__ raw, const int* __restrict__ flag,
                                     int* __restrict__ s32, int* __restrict__ d32,
                                     int* __restrict__ cnt, int E) {
  int e = blockIdx.x * blockDim.x + threadIdx.x;
  if (e >= E) return;
  int s, d;
  if (*flag) { s = raw[e];     d = raw[E + e]; }
  else       { s = raw[2 * e]; d = raw[2 * (E + e)]; }
  s32[e] = s; d32[e] = d;
  atomicAdd(&cnt[d], 1);
}

// single-block scan over counts -> exclusive row_start; also computes dinv
__global__ __launch_bounds__(1024) void scan_dinv_kernel(const int* __restrict__ cnt,
                                                         int* __restrict__ row_start,
                                                         float* __restrict__ dinv, int n) {
  __shared__ int wsum[16];
  __shared__ int carry_s;
  int tid = threadIdx.x, lane = tid & 63, wv = tid >> 6;
  if (tid == 0) carry_s = 0;
  __syncthreads();
  for (int base = 0; base < n; base += 1024) {
    int v = (base + tid < n) ? cnt[base + tid] : 0;
    if (base + tid < n) dinv[base + tid] = 1.0f / sqrtf((float)(v + 1));
    int x = v;                              // inclusive wave scan
#pragma unroll
    for (int off = 1; off < 64; off <<= 1) {
      int t = __shfl_up(x, off);
      if (lane >= off) x += t;
    }
    if (lane == 63) wsum[wv] = x;
    __syncthreads();
    int carry = carry_s;
    if (wv == 0) {
      int s = (lane < 16) ? wsum[lane] : 0;
#pragma unroll
      for (int off = 1; off < 16; off <<= 1) {
        int t = __shfl_up(s, off);
        if (lane >= off) s += t;
      }
      if (lane < 16) wsum[lane] = s;
    }
    __syncthreads();
    int woff = wv ? wsum[wv - 1] : 0;
    int total = wsum[15];
    if (base + tid < n) row_start[base + tid] = carry + woff + x - v;
    __syncthreads();
    if (tid == 0) carry_s = carry + total;
  }
  if (tid == 0) row_start[n] = carry_s;
}

__global__ void scatter_kernel(const int* __restrict__ s32, const int* __restrict__ d32,
                               const int* __restrict__ row_start, int* __restrict__ fill,
                               const float* __restrict__ dinv,
                               int* __restrict__ csr_src, float* __restrict__ csr_norm, int E) {
  int e = blockIdx.x * blockDim.x + threadIdx.x;
  if (e >= E) return;
  int s = s32[e], d = d32[e];
  int p = row_start[d] + atomicAdd(&fill[d], 1);
  csr_src[p] = s;
  csr_norm[p] = dinv[s] * dinv[d];
}

// ---------- W prep: fp32 W[k][n] -> bf16 hi/lo, MFMA fragment order; blocks 0-255 -> W1, 256-511 -> W2
// frag addr = ((ks*16 + g)*64 + ch*16 + ln)*8 + j  (ks=k>>5, ch=(k>>3)&3, j=k&7, g=n>>4, ln=n&15)
__global__ __launch_bounds__(256) void wprep_kernel(const float* __restrict__ W1,
                                                    const float* __restrict__ W2,
                                                    unsigned short* __restrict__ W1hi,
                                                    unsigned short* __restrict__ W1lo,
                                                    unsigned short* __restrict__ W2hi,
                                                    unsigned short* __restrict__ W2lo) {
  int which = blockIdx.x >> 8;
  int idx = (blockIdx.x & 255) * 256 + threadIdx.x;   // idx = k*256 + n
  const float* W = which ? W2 : W1;
  unsigned short* Whi = which ? W2hi : W1hi;
  unsigned short* Wlo = which ? W2lo : W1lo;
  int k = idx >> 8, n = idx & 255;
  float w = W[idx];
  unsigned short hi = f2bf(w);
  unsigned short lo = f2bf(w - bf2f(hi));
  int g = n >> 4, ln = n & 15;
  int ks = k >> 5, ch = (k >> 3) & 3, j = k & 7;
  int addr = ((ks * 16 + g) * 64 + ch * 16 + ln) * 8 + j;
  Whi[addr] = hi;
  Wlo[addr] = lo;
}

// ---------- MFMA GEMM, LDS-free: C[M,256] = A[M,256] @ W; A fp32 (L1) or bf16 (L2); C fp8 ----------
// W (hi+lo = 256KB, fragment-linear) is L1/L2-resident; each wave loads its fragments
// directly from global — no LDS, no barriers, occupancy limited only by VGPRs.
// wave = 32 rows x 128 cols; block = 4 waves = 2 row-tiles x 2 col-halves = 64 rows.
template <int AFP32>
__global__ __launch_bounds__(256) void gemm_mfma(const void* __restrict__ Av,
                                                 const unsigned short* __restrict__ Whi,
                                                 const unsigned short* __restrict__ Wlo,
                                                 unsigned int* __restrict__ C) {
  int tid = threadIdx.x, lane = tid & 63, wv = tid >> 6;
  int m0 = blockIdx.x * 64 + (wv >> 1) * 32;   // wave's 32-row tile
  int ch = wv & 1;                             // col half: 128 cols
  int mr0 = m0 + (lane & 15);
  int mr1 = mr0 + 16;
  if (mr0 >= MROWS) mr0 = MROWS - 1;           // clamp pad rows (output ignored)
  if (mr1 >= MROWS) mr1 = MROWS - 1;
  int kc = (lane >> 4) * 8;                    // k-chunk offset within BK=32

  const float* Af          = (const float*)Av;
  const unsigned short* Ab = (const unsigned short*)Av;

  floatx4 acc[2][8];
#pragma unroll
  for (int t = 0; t < 2; ++t)
#pragma unroll
    for (int g = 0; g < 8; ++g) acc[t][g] = (floatx4)(0.0f);

  auto load_a = [&](int mrow, int ks) -> bhalf8 {
    bhalf8 r;
    if (AFP32) {
      const float* p = &Af[(size_t)mrow * FEAT + ks * 32 + kc];
      float4 u = *(const float4*)p;
      float4 v = *(const float4*)(p + 4);
      r[0] = (short)f2bf(u.x); r[1] = (short)f2bf(u.y);
      r[2] = (short)f2bf(u.z); r[3] = (short)f2bf(u.w);
      r[4] = (short)f2bf(v.x); r[5] = (short)f2bf(v.y);
      r[6] = (short)f2bf(v.z); r[7] = (short)f2bf(v.w);
    } else {
      r = *(const bhalf8*)&Ab[(size_t)mrow * FEAT + ks * 32 + kc];
    }
    return r;
  };

  for (int ks = 0; ks < 8; ++ks) {
    bhalf8 a0 = load_a(mr0, ks);
    bhalf8 a1 = load_a(mr1, ks);
#pragma unroll
    for (int g = 0; g < 8; ++g) {
      size_t fa = ((size_t)(ks * 16 + ch * 8 + g) * 64 + lane) * 8;
      bhalf8 bh = *(const bhalf8*)&Whi[fa];    // lane-consecutive 16B: coalesced, L1-hot
      bhalf8 bl = *(const bhalf8*)&Wlo[fa];
      acc[0][g] = __builtin_amdgcn_mfma_f32_16x16x32_bf16(bh, a0, acc[0][g], 0, 0, 0);
      acc[0][g] = __builtin_amdgcn_mfma_f32_16x16x32_bf16(bl, a0, acc[0][g], 0, 0, 0);
      acc[1][g] = __builtin_amdgcn_mfma_f32_16x16x32_bf16(bh, a1, acc[1][g], 0, 0, 0);
      acc[1][g] = __builtin_amdgcn_mfma_f32_16x16x32_bf16(bl, a1, acc[1][g], 0, 0, 0);
    }
  }

  // D layout: m_local = lane&15, n_local = (lane>>4)*4 + reg; pack 4 cols -> 1 uint of fp8
  int nc = (lane >> 4) * 4;
#pragma unroll
  for (int t = 0; t < 2; ++t) {
    int om = m0 + t * 16 + (lane & 15);        // < MPAD, C is padded
#pragma unroll
    for (int g = 0; g < 8; ++g) {
      int col = (ch * 8 + g) * 16 + nc;
      C[(size_t)om * 64 + (col >> 2)] =
          pack4_fp8(acc[t][g][0], acc[t][g][1], acc[t][g][2], acc[t][g][3]);
    }
  }
}

// ---------- aggregation: out[b,n,:] = bf16(relu(bias + dinv^2*h[n] + sum norm*h[src])) ----------
// h is fp8 e4m3 (64 uints per 256-feat row); accumulate fp32; out bf16.
__global__ __launch_bounds__(128) void agg_kernel(const unsigned int* __restrict__ h8,
                                                  const int* __restrict__ row_start,
                                                  const int* __restrict__ csr_src,
                                                  const float* __restrict__ csr_norm,
                                                  const float* __restrict__ dinv,
                                                  const float* __restrict__ bias,
                                                  unsigned short* __restrict__ out) {
  int n = blockIdx.x;
  int b = threadIdx.x >> 6;          // wave 0 -> batch 0, wave 1 -> batch 1
  int lane = threadIdx.x & 63;       // 4 feats per lane: c = lane*4
  const unsigned int* hb = h8 + (size_t)b * NNODES * 64;
  float di = dinv[n];
  float sn = di * di;
  unsigned int v = hb[(size_t)n * 64 + lane];
  floatx2 v01 = __builtin_amdgcn_cvt_pk_f32_fp8((int)v, false);
  floatx2 v23 = __builtin_amdgcn_cvt_pk_f32_fp8((int)v, true);
  float4 acc = make_float4(v01[0] * sn, v01[1] * sn, v23[0] * sn, v23[1] * sn);
  int s0 = row_start[n], s1 = row_start[n + 1];
  int i = s0;
  for (; i + 2 <= s1; i += 2) {
    int sa = csr_src[i], sb = csr_src[i + 1];
    float wa = csr_norm[i], wb = csr_norm[i + 1];
    unsigned int ma = hb[(size_t)sa * 64 + lane];
    unsigned int mb = hb[(size_t)sb * 64 + lane];
    floatx2 a01 = __builtin_amdgcn_cvt_pk_f32_fp8((int)ma, false);
    floatx2 a23 = __builtin_amdgcn_cvt_pk_f32_fp8((int)ma, true);
    floatx2 b01 = __builtin_amdgcn_cvt_pk_f32_fp8((int)mb, false);
    floatx2 b23 = __builtin_amdgcn_cvt_pk_f32_fp8((int)mb, true);
    acc.x = fmaf(wa, a01[0], acc.x);
    acc.y = fmaf(wa, a01[1], acc.y);
    acc.z = fmaf(wa, a23[0], acc.z);
    acc.w = fmaf(wa, a23[1], acc.w);
    acc.x = fmaf(wb, b01[0], acc.x);
    acc.y = fmaf(wb, b01[1], acc.y);
    acc.z = fmaf(wb, b23[0], acc.z);
    acc.w = fmaf(wb, b23[1], acc.w);
  }
  if (i < s1) {
    int s = csr_src[i];
    float w = csr_norm[i];
    unsigned int m = hb[(size_t)s * 64 + lane];
    floatx2 a01 = __builtin_amdgcn_cvt_pk_f32_fp8((int)m, false);
    floatx2 a23 = __builtin_amdgcn_cvt_pk_f32_fp8((int)m, true);
    acc.x = fmaf(w, a01[0], acc.x);
    acc.y = fmaf(w, a01[1], acc.y);
    acc.z = fmaf(w, a23[0], acc.z);
    acc.w = fmaf(w, a23[1], acc.w);
  }
  int c = lane * 4;
  float4 bi = *(const float4*)&bias[c];
  ushort4 o;
  o.x = f2bf(fmaxf(acc.x + bi.x, 0.0f));
  o.y = f2bf(fmaxf(acc.y + bi.y, 0.0f));
  o.z = f2bf(fmaxf(acc.z + bi.z, 0.0f));
  o.w = f2bf(fmaxf(acc.w + bi.w, 0.0f));
  *(ushort4*)&out[((size_t)b * NNODES + n) * FEAT + c] = o;
}

// ---------- pooling (two-stage deterministic) + FC ----------
__global__ __launch_bounds__(256) void pool_partial(const unsigned short* __restrict__ h2,
                                                    float* __restrict__ partials) {
  int blk = blockIdx.x;
  int c = threadIdx.x;
  int chunk = NNODES / PBLK;          // 100
  int n0 = blk * chunk;
  float s0 = 0.f, s1 = 0.f;
  for (int n = n0; n < n0 + chunk; ++n) {
    s0 += bf2f(h2[((size_t)0 * NNODES + n) * FEAT + c]);
    s1 += bf2f(h2[((size_t)1 * NNODES + n) * FEAT + c]);
  }
  partials[(blk * 2 + 0) * FEAT + c] = s0;
  partials[(blk * 2 + 1) * FEAT + c] = s1;
}

__global__ __launch_bounds__(256) void pool_fc(const float* __restrict__ partials,
                                               const float* __restrict__ Wfc, const float* __restrict__ bfc,
                                               float* __restrict__ out) {
  __shared__ float pooled[BATCH][FEAT];
  int t = threadIdx.x;  // channel
  float s0 = 0.f, s1 = 0.f;
  for (int p = 0; p < PBLK; ++p) {
    s0 += partials[(p * 2 + 0) * FEAT + t];
    s1 += partials[(p * 2 + 1) * FEAT + t];
  }
  pooled[0][t] = s0 / (float)NNODES;
  pooled[1][t] = s1 / (float)NNODES;
  __syncthreads();
  if (t < BATCH * OOUT) {
    int b = t >> 6, o = t & 63;
    float acc = bfc[o];
    for (int c2 = 0; c2 < FEAT; ++c2)
      acc = fmaf(pooled[b][c2], Wfc[c2 * OOUT + o], acc);
    out[b * OOUT + o] = acc;
  }
}

extern "C" void kernel_launch(void* const* d_in, const int* in_sizes, int n_in,
                              void* d_out, int out_size, void* d_ws, size_t ws_size,
                              hipStream_t stream) {
  const float* x    = (const float*)d_in[0];
  const float* W1   = (const float*)d_in[1];
  const float* b1   = (const float*)d_in[2];
  const float* W2   = (const float*)d_in[3];
  const float* b2   = (const float*)d_in[4];
  const float* Wfc  = (const float*)d_in[5];
  const float* bfc  = (const float*)d_in[6];
  const int*   eraw = (const int*)d_in[7];
  int E = in_sizes[7] / 2;
  float* out = (float*)d_out;

  char* ws = (char*)d_ws;
  size_t off = 0;
  auto alloc = [&](size_t elems) -> void* {   // elems in 4-byte units
    void* p = ws + off * 4;
    off += (elems + 3) & ~(size_t)3;          // keep 16B alignment
    return p;
  };
  int*   flag      = (int*)alloc(4);
  int*   s32       = (int*)alloc(E);
  int*   d32       = (int*)alloc(E);
  int*   cnt       = (int*)alloc(NNODES);
  float* dinv      = (float*)alloc(NNODES);
  int*   row_start = (int*)alloc(NNODES + 1);
  int*   fill      = (int*)alloc(NNODES);
  int*   csr_src   = (int*)alloc(E);
  float* csr_norm  = (float*)alloc(E);
  unsigned short* w1hi = (unsigned short*)alloc(65536 / 2);
  unsigned short* w1lo = (unsigned short*)alloc(65536 / 2);
  unsigned short* w2hi = (unsigned short*)alloc(65536 / 2);
  unsigned short* w2lo = (unsigned short*)alloc(65536 / 2);
  unsigned int*   h8   = (unsigned int*)alloc((size_t)MPAD * 64);            // fp8 GEMM out (padded)
  unsigned short* a1   = (unsigned short*)alloc((size_t)MROWS * FEAT / 2);   // agg out, bf16
  float* partials  = (float*)alloc((size_t)PBLK * BATCH * FEAT);

  int eg = (E + 255) / 256;
  detect_zero_kernel<<<1, 256, 0, stream>>>(eraw, flag, cnt, fill, E);
  convert_count_kernel<<<eg, 256, 0, stream>>>(eraw, flag, s32, d32, cnt, E);
  scan_dinv_kernel<<<1, 1024, 0, stream>>>(cnt, row_start, dinv, NNODES);
  scatter_kernel<<<eg, 256, 0, stream>>>(s32, d32, row_start, fill, dinv, csr_src, csr_norm, E);
  wprep_kernel<<<512, 256, 0, stream>>>(W1, W2, w1hi, w1lo, w2hi, w2lo);

  gemm_mfma<1><<<MPAD / 64, 256, 0, stream>>>(x, w1hi, w1lo, h8);
  agg_kernel<<<NNODES, 128, 0, stream>>>(h8, row_start, csr_src, csr_norm, dinv, b1, a1);
  gemm_mfma<0><<<MPAD / 64, 256, 0, stream>>>(a1, w2hi, w2lo, h8);
  agg_kernel<<<NNODES, 128, 0, stream>>>(h8, row_start, csr_src, csr_norm, dinv, b2, a1);
  pool_partial<<<PBLK, 256, 0, stream>>>(a1, partials);
  pool_fc<<<1, 256, 0, stream>>>(partials, Wfc, bfc, out);
}

// Round 7
// 225.294 us; speedup vs baseline: 1.1600x; 1.1600x over previous
//
#include <hip/hip_runtime.h>

#define NNODES 20000
#define BATCH  2
#define FEAT   256
#define OOUT   64
#define PBLK   200
#define MROWS  (BATCH * NNODES)   // 40000
#define MPAD   40192              // 157 * 256

typedef short  bhalf8 __attribute__((ext_vector_type(8)));   // 8 bf16 in 4 VGPRs
typedef float  floatx4 __attribute__((ext_vector_type(4)));
typedef float  floatx2 __attribute__((ext_vector_type(2)));

// ---------- bf16 helpers ----------
__device__ __forceinline__ float bf2f(unsigned short u) {
  return __uint_as_float(((unsigned int)u) << 16);
}
__device__ __forceinline__ unsigned short f2bf(float f) {  // round-to-nearest-even
  unsigned int u = __float_as_uint(f);
  return (unsigned short)((u + 0x7fffu + ((u >> 16) & 1u)) >> 16);
}

// ---------- fp8 e4m3 helpers (HW converts, RNE) ----------
__device__ __forceinline__ unsigned int pack4_fp8(float a, float b, float c, float d) {
  int p = __builtin_amdgcn_cvt_pk_fp8_f32(a, b, 0, false);   // bytes 0,1
  p = __builtin_amdgcn_cvt_pk_fp8_f32(c, d, p, true);        // bytes 2,3
  return (unsigned int)p;
}

// ---------- detect edge dtype + zero cnt/fill (single block) ----------
__global__ __launch_bounds__(256) void detect_zero_kernel(const int* __restrict__ raw,
                                                          int* __restrict__ flag,
                                                          int* __restrict__ cnt,
                                                          int* __restrict__ fill, int E) {
  for (int i = threadIdx.x; i < NNODES; i += 256) { cnt[i] = 0; fill[i] = 0; }
  __shared__ int any;
  if (threadIdx.x == 0) any = 0;
  __syncthreads();
  int nchk = E < 2048 ? E : 2048;
  for (int i = threadIdx.x; i < nchk; i += blockDim.x)
    if (raw[2 * i + 1] != 0) any = 1;   // int64 high words are 0 (values < 20000)
  __syncthreads();
  if (threadIdx.x == 0) *flag = any;    // 1 => int32 layout, 0 => int64 layout
}

// ---------- convert + degree count ----------
__global__ void convert_count_kernel(const int* __restrict__ raw, const int* __restrict__ flag,
                                     int* __restrict__ s32, int* __restrict__ d32,
                                     int* __restrict__ cnt, int E) {
  int e = blockIdx.x * blockDim.x + threadIdx.x;
  if (e >= E) return;
  int s, d;
  if (*flag) { s = raw[e];     d = raw[E + e]; }
  else       { s = raw[2 * e]; d = raw[2 * (E + e)]; }
  s32[e] = s; d32[e] = d;
  atomicAdd(&cnt[d], 1);
}

// single-block scan over counts -> exclusive row_start; also computes dinv
__global__ __launch_bounds__(1024) void scan_dinv_kernel(const int* __restrict__ cnt,
                                                         int* __restrict__ row_start,
                                                         float* __restrict__ dinv, int n) {
  __shared__ int wsum[16];
  __shared__ int carry_s;
  int tid = threadIdx.x, lane = tid & 63, wv = tid >> 6;
  if (tid == 0) carry_s = 0;
  __syncthreads();
  for (int base = 0; base < n; base += 1024) {
    int v = (base + tid < n) ? cnt[base + tid] : 0;
    if (base + tid < n) dinv[base + tid] = 1.0f / sqrtf((float)(v + 1));
    int x = v;                              // inclusive wave scan
#pragma unroll
    for (int off = 1; off < 64; off <<= 1) {
      int t = __shfl_up(x, off);
      if (lane >= off) x += t;
    }
    if (lane == 63) wsum[wv] = x;
    __syncthreads();
    int carry = carry_s;
    if (wv == 0) {
      int s = (lane < 16) ? wsum[lane] : 0;
#pragma unroll
      for (int off = 1; off < 16; off <<= 1) {
        int t = __shfl_up(s, off);
        if (lane >= off) s += t;
      }
      if (lane < 16) wsum[lane] = s;
    }
    __syncthreads();
    int woff = wv ? wsum[wv - 1] : 0;
    int total = wsum[15];
    if (base + tid < n) row_start[base + tid] = carry + woff + x - v;
    __syncthreads();
    if (tid == 0) carry_s = carry + total;
  }
  if (tid == 0) row_start[n] = carry_s;
}

__global__ void scatter_kernel(const int* __restrict__ s32, const int* __restrict__ d32,
                               const int* __restrict__ row_start, int* __restrict__ fill,
                               const float* __restrict__ dinv,
                               int* __restrict__ csr_src, float* __restrict__ csr_norm, int E) {
  int e = blockIdx.x * blockDim.x + threadIdx.x;
  if (e >= E) return;
  int s = s32[e], d = d32[e];
  int p = row_start[d] + atomicAdd(&fill[d], 1);
  csr_src[p] = s;
  csr_norm[p] = dinv[s] * dinv[d];
}

// ---------- W prep: fp32 W[k][n] -> bf16 hi/lo, MFMA fragment order; blocks 0-255 -> W1, 256-511 -> W2
// frag addr = ((ks*16 + g)*64 + ch*16 + ln)*8 + j  (ks=k>>5, ch=(k>>3)&3, j=k&7, g=n>>4, ln=n&15)
__global__ __launch_bounds__(256) void wprep_kernel(const float* __restrict__ W1,
                                                    const float* __restrict__ W2,
                                                    unsigned short* __restrict__ W1hi,
                                                    unsigned short* __restrict__ W1lo,
                                                    unsigned short* __restrict__ W2hi,
                                                    unsigned short* __restrict__ W2lo) {
  int which = blockIdx.x >> 8;
  int idx = (blockIdx.x & 255) * 256 + threadIdx.x;   // idx = k*256 + n
  const float* W = which ? W2 : W1;
  unsigned short* Whi = which ? W2hi : W1hi;
  unsigned short* Wlo = which ? W2lo : W1lo;
  int k = idx >> 8, n = idx & 255;
  float w = W[idx];
  unsigned short hi = f2bf(w);
  unsigned short lo = f2bf(w - bf2f(hi));
  int g = n >> 4, ln = n & 15;
  int ks = k >> 5, ch = (k >> 3) & 3, j = k & 7;
  int addr = ((ks * 16 + g) * 64 + ch * 16 + ln) * 8 + j;
  Whi[addr] = hi;
  Wlo[addr] = lo;
}

// ---------- MFMA GEMM: W-quarter persistent in LDS, no K-loop barriers ----------
// Block = 4 waves x 64 rows = 256 rows, covering a 64-col quarter (blockIdx.y).
// LDS = W[:, quarter] hi+lo in fragment order = 64 KB, filled once.
// Per wave per ks: 4 A loads, 8 ds_read_b128, 32 MFMA (4 MFMA per ds_read).
template <int AFP32>
__global__ __launch_bounds__(256) void gemm_mfma(const void* __restrict__ Av,
                                                 const unsigned short* __restrict__ Whi,
                                                 const unsigned short* __restrict__ Wlo,
                                                 unsigned int* __restrict__ C) {
  __shared__ unsigned short lds[32768];   // hi: [ks][g][lane][8] = 16384 ushorts; lo at +16384
  int tid = threadIdx.x, lane = tid & 63, wv = tid >> 6;
  int q = blockIdx.y;                     // col quarter
  int bm = blockIdx.x * 256;

  // fill LDS: hi slice units u = (ks*4+g)*64 + l  (2048 bhalf8 units each for hi/lo)
#pragma unroll
  for (int c = 0; c < 8; ++c) {
    int u = c * 256 + tid;                // [0, 2048)
    int ks = u >> 8, g = (u >> 6) & 3, l = u & 63;
    size_t ga = ((size_t)(ks * 16 + q * 4 + g) * 64 + l) * 8;
    *(bhalf8*)&lds[(size_t)u * 8] = *(const bhalf8*)&Whi[ga];
    *(bhalf8*)&lds[16384 + (size_t)u * 8] = *(const bhalf8*)&Wlo[ga];
  }
  __syncthreads();                        // the only barrier

  const float* Af          = (const float*)Av;
  const unsigned short* Ab = (const unsigned short*)Av;
  int kc = (lane >> 4) * 8;               // k-chunk offset within BK=32

  int mr[4];
#pragma unroll
  for (int t = 0; t < 4; ++t) {
    int m = bm + wv * 64 + t * 16 + (lane & 15);
    mr[t] = m >= MROWS ? MROWS - 1 : m;   // clamp pad rows (output ignored)
  }

  floatx4 acc[4][4];
#pragma unroll
  for (int t = 0; t < 4; ++t)
#pragma unroll
    for (int g = 0; g < 4; ++g) acc[t][g] = (floatx4)(0.0f);

  auto load_a = [&](int ks, bhalf8 (&a)[4]) {
#pragma unroll
    for (int t = 0; t < 4; ++t) {
      if (AFP32) {
        const float* p = &Af[(size_t)mr[t] * FEAT + ks * 32 + kc];
        float4 u = *(const float4*)p;
        float4 v = *(const float4*)(p + 4);
        a[t][0] = (short)f2bf(u.x); a[t][1] = (short)f2bf(u.y);
        a[t][2] = (short)f2bf(u.z); a[t][3] = (short)f2bf(u.w);
        a[t][4] = (short)f2bf(v.x); a[t][5] = (short)f2bf(v.y);
        a[t][6] = (short)f2bf(v.z); a[t][7] = (short)f2bf(v.w);
      } else {
        a[t] = *(const bhalf8*)&Ab[(size_t)mr[t] * FEAT + ks * 32 + kc];
      }
    }
  };
  auto step = [&](int ks, bhalf8 (&a)[4]) {
#pragma unroll
    for (int g = 0; g < 4; ++g) {
      bhalf8 bh = *(const bhalf8*)&lds[(size_t)(ks * 4 + g) * 512 + lane * 8];
      bhalf8 bl = *(const bhalf8*)&lds[16384 + (size_t)(ks * 4 + g) * 512 + lane * 8];
#pragma unroll
      for (int t = 0; t < 4; ++t)
        acc[t][g] = __builtin_amdgcn_mfma_f32_16x16x32_bf16(bh, a[t], acc[t][g], 0, 0, 0);
#pragma unroll
      for (int t = 0; t < 4; ++t)
        acc[t][g] = __builtin_amdgcn_mfma_f32_16x16x32_bf16(bl, a[t], acc[t][g], 0, 0, 0);
    }
  };

  bhalf8 aE[4], aO[4];
  load_a(0, aE);
#pragma unroll
  for (int kp = 0; kp < 4; ++kp) {        // 2 K-steps per iter, A prefetched 1 step ahead
    load_a(kp * 2 + 1, aO);
    step(kp * 2, aE);
    if (kp < 3) load_a(kp * 2 + 2, aE);
    step(kp * 2 + 1, aO);
  }

  // D layout: m_local = lane&15, n_local = (lane>>4)*4 + reg; pack 4 cols -> 1 uint of fp8
  int nc = (lane >> 4) * 4;
#pragma unroll
  for (int t = 0; t < 4; ++t) {
    int om = bm + wv * 64 + t * 16 + (lane & 15);   // < MPAD, C is padded
#pragma unroll
    for (int g = 0; g < 4; ++g) {
      int col = (q * 4 + g) * 16 + nc;
      C[(size_t)om * 64 + (col >> 2)] =
          pack4_fp8(acc[t][g][0], acc[t][g][1], acc[t][g][2], acc[t][g][3]);
    }
  }
}

// ---------- aggregation: out[b,n,:] = bf16(relu(bias + dinv^2*h[n] + sum norm*h[src])) ----------
// h fp8 e4m3 as uint2 (8 feats/lane); lanes 0-31 even edges, 32-63 odd edges (2 edges in
// flight per wave instruction); halves combined via shfl_xor(32) at the end.
__global__ __launch_bounds__(128) void agg_kernel(const uint2* __restrict__ h8,
                                                  const int* __restrict__ row_start,
                                                  const int* __restrict__ csr_src,
                                                  const float* __restrict__ csr_norm,
                                                  const float* __restrict__ dinv,
                                                  const float* __restrict__ bias,
                                                  unsigned short* __restrict__ out) {
  int n = blockIdx.x;
  int b = threadIdx.x >> 6;          // wave 0 -> batch 0, wave 1 -> batch 1
  int lane = threadIdx.x & 63;
  int half = lane >> 5;              // 0: even edges, 1: odd edges
  int cl = lane & 31;                // feats c = cl*8 .. cl*8+7
  const uint2* hb = h8 + (size_t)b * NNODES * 32;
  float di = dinv[n];
  float sn = half ? 0.0f : di * di;  // self term on half 0 only
  uint2 v = hb[(size_t)n * 32 + cl];
  floatx2 p01 = __builtin_amdgcn_cvt_pk_f32_fp8((int)v.x, false);
  floatx2 p23 = __builtin_amdgcn_cvt_pk_f32_fp8((int)v.x, true);
  floatx2 p45 = __builtin_amdgcn_cvt_pk_f32_fp8((int)v.y, false);
  floatx2 p67 = __builtin_amdgcn_cvt_pk_f32_fp8((int)v.y, true);
  float a0 = p01[0] * sn, a1 = p01[1] * sn, a2 = p23[0] * sn, a3 = p23[1] * sn;
  float a4 = p45[0] * sn, a5 = p45[1] * sn, a6 = p67[0] * sn, a7 = p67[1] * sn;
  int s0 = row_start[n], s1 = row_start[n + 1];

  auto edge = [&](int i) {
    int s = csr_src[i];
    float w = csr_norm[i];
    uint2 m = hb[(size_t)s * 32 + cl];
    floatx2 q01 = __builtin_amdgcn_cvt_pk_f32_fp8((int)m.x, false);
    floatx2 q23 = __builtin_amdgcn_cvt_pk_f32_fp8((int)m.x, true);
    floatx2 q45 = __builtin_amdgcn_cvt_pk_f32_fp8((int)m.y, false);
    floatx2 q67 = __builtin_amdgcn_cvt_pk_f32_fp8((int)m.y, true);
    a0 = fmaf(w, q01[0], a0); a1 = fmaf(w, q01[1], a1);
    a2 = fmaf(w, q23[0], a2); a3 = fmaf(w, q23[1], a3);
    a4 = fmaf(w, q45[0], a4); a5 = fmaf(w, q45[1], a5);
    a6 = fmaf(w, q67[0], a6); a7 = fmaf(w, q67[1], a7);
  };
  int i = s0 + half;
  for (; i + 2 < s1; i += 4) { edge(i); edge(i + 2); }   // 4 edges per wave iteration
  if (i < s1) edge(i);

  // combine even/odd halves (each channel owned by lane cl and cl+32)
  a0 += __shfl_xor(a0, 32); a1 += __shfl_xor(a1, 32);
  a2 += __shfl_xor(a2, 32); a3 += __shfl_xor(a3, 32);
  a4 += __shfl_xor(a4, 32); a5 += __shfl_xor(a5, 32);
  a6 += __shfl_xor(a6, 32); a7 += __shfl_xor(a7, 32);

  if (half == 0) {
    int c = cl * 8;
    float4 b0 = *(const float4*)&bias[c];
    float4 b1 = *(const float4*)&bias[c + 4];
    uint4 o;
    o.x = (unsigned int)f2bf(fmaxf(a0 + b0.x, 0.0f)) | ((unsigned int)f2bf(fmaxf(a1 + b0.y, 0.0f)) << 16);
    o.y = (unsigned int)f2bf(fmaxf(a2 + b0.z, 0.0f)) | ((unsigned int)f2bf(fmaxf(a3 + b0.w, 0.0f)) << 16);
    o.z = (unsigned int)f2bf(fmaxf(a4 + b1.x, 0.0f)) | ((unsigned int)f2bf(fmaxf(a5 + b1.y, 0.0f)) << 16);
    o.w = (unsigned int)f2bf(fmaxf(a6 + b1.z, 0.0f)) | ((unsigned int)f2bf(fmaxf(a7 + b1.w, 0.0f)) << 16);
    *(uint4*)&out[((size_t)b * NNODES + n) * FEAT + c] = o;
  }
}

// ---------- pooling (two-stage deterministic) + FC ----------
__global__ __launch_bounds__(256) void pool_partial(const unsigned short* __restrict__ h2,
                                                    float* __restrict__ partials) {
  int blk = blockIdx.x;
  int c = threadIdx.x;
  int chunk = NNODES / PBLK;          // 100
  int n0 = blk * chunk;
  float s0 = 0.f, s1 = 0.f;
  for (int n = n0; n < n0 + chunk; ++n) {
    s0 += bf2f(h2[((size_t)0 * NNODES + n) * FEAT + c]);
    s1 += bf2f(h2[((size_t)1 * NNODES + n) * FEAT + c]);
  }
  partials[(blk * 2 + 0) * FEAT + c] = s0;
  partials[(blk * 2 + 1) * FEAT + c] = s1;
}

__global__ __launch_bounds__(256) void pool_fc(const float* __restrict__ partials,
                                               const float* __restrict__ Wfc, const float* __restrict__ bfc,
                                               float* __restrict__ out) {
  __shared__ float pooled[BATCH][FEAT];
  int t = threadIdx.x;  // channel
  float s0 = 0.f, s1 = 0.f;
  for (int p = 0; p < PBLK; ++p) {
    s0 += partials[(p * 2 + 0) * FEAT + t];
    s1 += partials[(p * 2 + 1) * FEAT + t];
  }
  pooled[0][t] = s0 / (float)NNODES;
  pooled[1][t] = s1 / (float)NNODES;
  __syncthreads();
  if (t < BATCH * OOUT) {
    int b = t >> 6, o = t & 63;
    float acc = bfc[o];
    for (int c2 = 0; c2 < FEAT; ++c2)
      acc = fmaf(pooled[b][c2], Wfc[c2 * OOUT + o], acc);
    out[b * OOUT + o] = acc;
  }
}

extern "C" void kernel_launch(void* const* d_in, const int* in_sizes, int n_in,
                              void* d_out, int out_size, void* d_ws, size_t ws_size,
                              hipStream_t stream) {
  const float* x    = (const float*)d_in[0];
  const float* W1   = (const float*)d_in[1];
  const float* b1   = (const float*)d_in[2];
  const float* W2   = (const float*)d_in[3];
  const float* b2   = (const float*)d_in[4];
  const float* Wfc  = (const float*)d_in[5];
  const float* bfc  = (const float*)d_in[6];
  const int*   eraw = (const int*)d_in[7];
  int E = in_sizes[7] / 2;
  float* out = (float*)d_out;

  char* ws = (char*)d_ws;
  size_t off = 0;
  auto alloc = [&](size_t elems) -> void* {   // elems in 4-byte units
    void* p = ws + off * 4;
    off += (elems + 3) & ~(size_t)3;          // keep 16B alignment
    return p;
  };
  int*   flag      = (int*)alloc(4);
  int*   s32       = (int*)alloc(E);
  int*   d32       = (int*)alloc(E);
  int*   cnt       = (int*)alloc(NNODES);
  float* dinv      = (float*)alloc(NNODES);
  int*   row_start = (int*)alloc(NNODES + 1);
  int*   fill      = (int*)alloc(NNODES);
  int*   csr_src   = (int*)alloc(E);
  float* csr_norm  = (float*)alloc(E);
  unsigned short* w1hi = (unsigned short*)alloc(65536 / 2);
  unsigned short* w1lo = (unsigned short*)alloc(65536 / 2);
  unsigned short* w2hi = (unsigned short*)alloc(65536 / 2);
  unsigned short* w2lo = (unsigned short*)alloc(65536 / 2);
  unsigned int*   h8   = (unsigned int*)alloc((size_t)MPAD * 64);            // fp8 GEMM out (padded)
  unsigned short* a1   = (unsigned short*)alloc((size_t)MROWS * FEAT / 2);   // agg out, bf16
  float* partials  = (float*)alloc((size_t)PBLK * BATCH * FEAT);

  int eg = (E + 255) / 256;
  detect_zero_kernel<<<1, 256, 0, stream>>>(eraw, flag, cnt, fill, E);
  convert_count_kernel<<<eg, 256, 0, stream>>>(eraw, flag, s32, d32, cnt, E);
  scan_dinv_kernel<<<1, 1024, 0, stream>>>(cnt, row_start, dinv, NNODES);
  scatter_kernel<<<eg, 256, 0, stream>>>(s32, d32, row_start, fill, dinv, csr_src, csr_norm, E);
  wprep_kernel<<<512, 256, 0, stream>>>(W1, W2, w1hi, w1lo, w2hi, w2lo);

  dim3 ggrid(MPAD / 256, 4);
  gemm_mfma<1><<<ggrid, 256, 0, stream>>>(x, w1hi, w1lo, h8);
  agg_kernel<<<NNODES, 128, 0, stream>>>((const uint2*)h8, row_start, csr_src, csr_norm, dinv, b1, a1);
  gemm_mfma<0><<<ggrid, 256, 0, stream>>>(a1, w2hi, w2lo, h8);
  agg_kernel<<<NNODES, 128, 0, stream>>>((const uint2*)h8, row_start, csr_src, csr_norm, dinv, b2, a1);
  pool_partial<<<PBLK, 256, 0, stream>>>(a1, partials);
  pool_fc<<<1, 256, 0, stream>>>(partials, Wfc, bfc, out);
}

// Round 8
// 203.013 us; speedup vs baseline: 1.2874x; 1.1097x over previous
//
#include <hip/hip_runtime.h>

#define NNODES 20000
#define BATCH  2
#define FEAT   256
#define OOUT   64
#define PBLK   200
#define MROWS  (BATCH * NNODES)   // 40000
#define MPAD   40192              // 314 * 128

typedef short  bhalf8 __attribute__((ext_vector_type(8)));   // 8 bf16 in 4 VGPRs
typedef float  floatx4 __attribute__((ext_vector_type(4)));
typedef float  floatx2 __attribute__((ext_vector_type(2)));

// ---------- bf16 helpers ----------
__device__ __forceinline__ float bf2f(unsigned short u) {
  return __uint_as_float(((unsigned int)u) << 16);
}
__device__ __forceinline__ unsigned short f2bf(float f) {  // round-to-nearest-even
  unsigned int u = __float_as_uint(f);
  return (unsigned short)((u + 0x7fffu + ((u >> 16) & 1u)) >> 16);
}

// ---------- fp8 e4m3 helpers (HW converts, RNE) ----------
__device__ __forceinline__ unsigned int pack4_fp8(float a, float b, float c, float d) {
  int p = __builtin_amdgcn_cvt_pk_fp8_f32(a, b, 0, false);   // bytes 0,1
  p = __builtin_amdgcn_cvt_pk_fp8_f32(c, d, p, true);        // bytes 2,3
  return (unsigned int)p;
}

// ---------- detect edge dtype + zero cnt/fill (single block) ----------
__global__ __launch_bounds__(256) void detect_zero_kernel(const int* __restrict__ raw,
                                                          int* __restrict__ flag,
                                                          int* __restrict__ cnt,
                                                          int* __restrict__ fill, int E) {
  for (int i = threadIdx.x; i < NNODES; i += 256) { cnt[i] = 0; fill[i] = 0; }
  __shared__ int any;
  if (threadIdx.x == 0) any = 0;
  __syncthreads();
  int nchk = E < 2048 ? E : 2048;
  for (int i = threadIdx.x; i < nchk; i += blockDim.x)
    if (raw[2 * i + 1] != 0) any = 1;   // int64 high words are 0 (values < 20000)
  __syncthreads();
  if (threadIdx.x == 0) *flag = any;    // 1 => int32 layout, 0 => int64 layout
}

// ---------- convert + degree count ----------
__global__ void convert_count_kernel(const int* __restrict__ raw, const int* __restrict__ flag,
                                     int* __restrict__ s32, int* __restrict__ d32,
                                     int* __restrict__ cnt, int E) {
  int e = blockIdx.x * blockDim.x + threadIdx.x;
  if (e >= E) return;
  int s, d;
  if (*flag) { s = raw[e];     d = raw[E + e]; }
  else       { s = raw[2 * e]; d = raw[2 * (E + e)]; }
  s32[e] = s; d32[e] = d;
  atomicAdd(&cnt[d], 1);
}

// single-block scan over counts -> exclusive row_start; also computes dinv
__global__ __launch_bounds__(1024) void scan_dinv_kernel(const int* __restrict__ cnt,
                                                         int* __restrict__ row_start,
                                                         float* __restrict__ dinv, int n) {
  __shared__ int wsum[16];
  __shared__ int carry_s;
  int tid = threadIdx.x, lane = tid & 63, wv = tid >> 6;
  if (tid == 0) carry_s = 0;
  __syncthreads();
  for (int base = 0; base < n; base += 1024) {
    int v = (base + tid < n) ? cnt[base + tid] : 0;
    if (base + tid < n) dinv[base + tid] = 1.0f / sqrtf((float)(v + 1));
    int x = v;                              // inclusive wave scan
#pragma unroll
    for (int off = 1; off < 64; off <<= 1) {
      int t = __shfl_up(x, off);
      if (lane >= off) x += t;
    }
    if (lane == 63) wsum[wv] = x;
    __syncthreads();
    int carry = carry_s;
    if (wv == 0) {
      int s = (lane < 16) ? wsum[lane] : 0;
#pragma unroll
      for (int off = 1; off < 16; off <<= 1) {
        int t = __shfl_up(s, off);
        if (lane >= off) s += t;
      }
      if (lane < 16) wsum[lane] = s;
    }
    __syncthreads();
    int woff = wv ? wsum[wv - 1] : 0;
    int total = wsum[15];
    if (base + tid < n) row_start[base + tid] = carry + woff + x - v;
    __syncthreads();
    if (tid == 0) carry_s = carry + total;
  }
  if (tid == 0) row_start[n] = carry_s;
}

__global__ void scatter_kernel(const int* __restrict__ s32, const int* __restrict__ d32,
                               const int* __restrict__ row_start, int* __restrict__ fill,
                               const float* __restrict__ dinv,
                               int* __restrict__ csr_src, float* __restrict__ csr_norm, int E) {
  int e = blockIdx.x * blockDim.x + threadIdx.x;
  if (e >= E) return;
  int s = s32[e], d = d32[e];
  int p = row_start[d] + atomicAdd(&fill[d], 1);
  csr_src[p] = s;
  csr_norm[p] = dinv[s] * dinv[d];
}

// ---------- W prep: fp32 W[k][n] -> bf16 hi/lo, MFMA fragment order; blocks 0-255 -> W1, 256-511 -> W2
// frag addr = ((ks*16 + g)*64 + ch*16 + ln)*8 + j  (ks=k>>5, ch=(k>>3)&3, j=k&7, g=n>>4, ln=n&15)
__global__ __launch_bounds__(256) void wprep_kernel(const float* __restrict__ W1,
                                                    const float* __restrict__ W2,
                                                    unsigned short* __restrict__ W1hi,
                                                    unsigned short* __restrict__ W1lo,
                                                    unsigned short* __restrict__ W2hi,
                                                    unsigned short* __restrict__ W2lo) {
  int which = blockIdx.x >> 8;
  int idx = (blockIdx.x & 255) * 256 + threadIdx.x;   // idx = k*256 + n
  const float* W = which ? W2 : W1;
  unsigned short* Whi = which ? W2hi : W1hi;
  unsigned short* Wlo = which ? W2lo : W1lo;
  int k = idx >> 8, n = idx & 255;
  float w = W[idx];
  unsigned short hi = f2bf(w);
  unsigned short lo = f2bf(w - bf2f(hi));
  int g = n >> 4, ln = n & 15;
  int ks = k >> 5, ch = (k >> 3) & 3, j = k & 7;
  int addr = ((ks * 16 + g) * 64 + ch * 16 + ln) * 8 + j;
  Whi[addr] = hi;
  Wlo[addr] = lo;
}

// ---------- MFMA GEMM: half-N blocks, 32KiB dbuf LDS, 1 barrier/K-step ----------
// Block = 4 waves x 32 rows = 128 rows, covering a 128-col half (blockIdx.y).
// Per wave per ks: 2 A loads, 16 ds_read_b128, 32 MFMA (2:1 MFMA:ds).
template <int AFP32>
__global__ __launch_bounds__(256) void gemm_mfma(const void* __restrict__ Av,
                                                 const unsigned short* __restrict__ Whi,
                                                 const unsigned short* __restrict__ Wlo,
                                                 unsigned int* __restrict__ C) {
  __shared__ unsigned short lds[2][8192];   // 2 x 16KiB: [hl][g][lane][8] per buf
  int tid = threadIdx.x, lane = tid & 63, wv = tid >> 6;
  int half = blockIdx.y;                    // col half (128 cols = groups half*8..half*8+7)
  int bm = blockIdx.x * 128;
  int kc = (lane >> 4) * 8;                 // k-chunk offset within BK=32

  const float* Af          = (const float*)Av;
  const unsigned short* Ab = (const unsigned short*)Av;

  int mr[2];
#pragma unroll
  for (int t = 0; t < 2; ++t) {
    int m = bm + wv * 32 + t * 16 + (lane & 15);
    mr[t] = m >= MROWS ? MROWS - 1 : m;     // clamp pad rows (output ignored)
  }

  floatx4 acc[2][8];
#pragma unroll
  for (int t = 0; t < 2; ++t)
#pragma unroll
    for (int g = 0; g < 8; ++g) acc[t][g] = (floatx4)(0.0f);

  bhalf8 st[4];   // staging regs: 4 x 16B per thread = one 16KiB K-slice per block

  auto stage_load = [&](int ks) {
#pragma unroll
    for (int i2 = 0; i2 < 4; ++i2) {
      int u = i2 * 256 + tid;               // u = hl*512 + g*64 + l
      int hl = u >> 9, g = (u >> 6) & 7, l = u & 63;
      const unsigned short* Wp = hl ? Wlo : Whi;
      st[i2] = *(const bhalf8*)&Wp[((size_t)(ks * 16 + half * 8 + g) * 64 + l) * 8];
    }
  };
  auto stage_write = [&](int buf) {
#pragma unroll
    for (int i2 = 0; i2 < 4; ++i2) {
      int u = i2 * 256 + tid;
      *(bhalf8*)&lds[buf][(size_t)u * 8] = st[i2];
    }
  };
  auto load_a = [&](int ks, bhalf8 (&a)[2]) {
#pragma unroll
    for (int t = 0; t < 2; ++t) {
      if (AFP32) {
        const float* p = &Af[(size_t)mr[t] * FEAT + ks * 32 + kc];
        float4 u = *(const float4*)p;
        float4 v = *(const float4*)(p + 4);
        a[t][0] = (short)f2bf(u.x); a[t][1] = (short)f2bf(u.y);
        a[t][2] = (short)f2bf(u.z); a[t][3] = (short)f2bf(u.w);
        a[t][4] = (short)f2bf(v.x); a[t][5] = (short)f2bf(v.y);
        a[t][6] = (short)f2bf(v.z); a[t][7] = (short)f2bf(v.w);
      } else {
        a[t] = *(const bhalf8*)&Ab[(size_t)mr[t] * FEAT + ks * 32 + kc];
      }
    }
  };
  auto step = [&](int buf, bhalf8 (&a)[2]) {
#pragma unroll
    for (int g = 0; g < 8; ++g) {
      bhalf8 bh = *(const bhalf8*)&lds[buf][((size_t)g * 64 + lane) * 8];          // hi
      bhalf8 bl = *(const bhalf8*)&lds[buf][((size_t)(512 + g * 64) + lane) * 8];  // lo
#pragma unroll
      for (int t = 0; t < 2; ++t)
        acc[t][g] = __builtin_amdgcn_mfma_f32_16x16x32_bf16(bh, a[t], acc[t][g], 0, 0, 0);
#pragma unroll
      for (int t = 0; t < 2; ++t)
        acc[t][g] = __builtin_amdgcn_mfma_f32_16x16x32_bf16(bl, a[t], acc[t][g], 0, 0, 0);
    }
  };

  stage_load(0);
  stage_write(0);
  __syncthreads();
  bhalf8 aC[2];
  load_a(0, aC);
  int cur = 0;
#pragma unroll
  for (int ks = 0; ks < 8; ++ks) {
    bhalf8 aN[2];
    if (ks < 7) {
      stage_load(ks + 1);       // global->reg, in flight under MFMAs
      load_a(ks + 1, aN);
    }
    step(cur, aC);
    if (ks < 7) {
      stage_write(cur ^ 1);     // write other buffer (no conflict with this step's reads)
      __syncthreads();          // one barrier per K-step
      aC[0] = aN[0]; aC[1] = aN[1];
    }
    cur ^= 1;
  }

  // D layout: m_local = lane&15, n_local = (lane>>4)*4 + reg; pack 4 cols -> 1 uint of fp8
  int nc = (lane >> 4) * 4;
#pragma unroll
  for (int t = 0; t < 2; ++t) {
    int om = bm + wv * 32 + t * 16 + (lane & 15);   // < MPAD, C is padded
#pragma unroll
    for (int g = 0; g < 8; ++g) {
      int col = (half * 8 + g) * 16 + nc;
      C[(size_t)om * 64 + (col >> 2)] =
          pack4_fp8(acc[t][g][0], acc[t][g][1], acc[t][g][2], acc[t][g][3]);
    }
  }
}

// ---------- aggregation: out[b,n,:] = bf16(relu(bias + dinv^2*h[n] + sum norm*h[src])) ----------
// h fp8 e4m3, rows = 16 uint4. Lanes split 4 ways: slot q = lane>>4 handles edges
// i = s0+q, s0+q+4, ... ; each 16-lane group loads one full 256B row (uint4/lane).
// 2-deep unroll => 8 gathers in flight per wave. Combine via shfl_xor(16,32).
__global__ __launch_bounds__(128) void agg_kernel(const uint4* __restrict__ h8,
                                                  const int* __restrict__ row_start,
                                                  const int* __restrict__ csr_src,
                                                  const float* __restrict__ csr_norm,
                                                  const float* __restrict__ dinv,
                                                  const float* __restrict__ bias,
                                                  unsigned short* __restrict__ out) {
  int n = blockIdx.x;
  int b = threadIdx.x >> 6;          // wave 0 -> batch 0, wave 1 -> batch 1
  int lane = threadIdx.x & 63;
  int q = lane >> 4;                 // edge slot 0..3
  int cl = lane & 15;                // uint4 index in row; feats cl*16 .. cl*16+15
  const uint4* hb = h8 + (size_t)b * NNODES * 16;

  float a[16];
#pragma unroll
  for (int j = 0; j < 16; ++j) a[j] = 0.0f;

  auto dec_fma = [&](uint4 m, float w) {
    unsigned int mm[4] = {m.x, m.y, m.z, m.w};
#pragma unroll
    for (int j = 0; j < 4; ++j) {
      floatx2 lo = __builtin_amdgcn_cvt_pk_f32_fp8((int)mm[j], false);
      floatx2 hi = __builtin_amdgcn_cvt_pk_f32_fp8((int)mm[j], true);
      a[j * 4 + 0] = fmaf(w, lo[0], a[j * 4 + 0]);
      a[j * 4 + 1] = fmaf(w, lo[1], a[j * 4 + 1]);
      a[j * 4 + 2] = fmaf(w, hi[0], a[j * 4 + 2]);
      a[j * 4 + 3] = fmaf(w, hi[1], a[j * 4 + 3]);
    }
  };

  float di = dinv[n];
  if (q == 0) dec_fma(hb[(size_t)n * 16 + cl], di * di);   // self term on slot 0

  int s0 = row_start[n], s1 = row_start[n + 1];
  int i = s0 + q;
  for (; i + 4 < s1; i += 8) {       // 2 edges per slot-iter; 8 gathers in flight per wave
    int sa = csr_src[i], sb = csr_src[i + 4];
    float wa = csr_norm[i], wb = csr_norm[i + 4];
    uint4 ma = hb[(size_t)sa * 16 + cl];
    uint4 mb = hb[(size_t)sb * 16 + cl];
    dec_fma(ma, wa);
    dec_fma(mb, wb);
  }
  if (i < s1) dec_fma(hb[(size_t)csr_src[i] * 16 + cl], csr_norm[i]);

  // combine 4 slots (same cl across q): xor 16 then xor 32
#pragma unroll
  for (int j = 0; j < 16; ++j) {
    a[j] += __shfl_xor(a[j], 16);
    a[j] += __shfl_xor(a[j], 32);
  }

  if (q == 0) {
    int c = cl * 16;
    unsigned short o[16];
#pragma unroll
    for (int j = 0; j < 16; ++j)
      o[j] = f2bf(fmaxf(a[j] + bias[c + j], 0.0f));
    unsigned short* dst = &out[((size_t)b * NNODES + n) * FEAT + c];
    *(uint4*)dst = *(uint4*)&o[0];
    *(uint4*)(dst + 8) = *(uint4*)&o[8];
  }
}

// ---------- pooling (two-stage deterministic) + FC ----------
__global__ __launch_bounds__(256) void pool_partial(const unsigned short* __restrict__ h2,
                                                    float* __restrict__ partials) {
  int blk = blockIdx.x;
  int c = threadIdx.x;
  int chunk = NNODES / PBLK;          // 100
  int n0 = blk * chunk;
  float s0 = 0.f, s1 = 0.f;
  for (int n = n0; n < n0 + chunk; ++n) {
    s0 += bf2f(h2[((size_t)0 * NNODES + n) * FEAT + c]);
    s1 += bf2f(h2[((size_t)1 * NNODES + n) * FEAT + c]);
  }
  partials[(blk * 2 + 0) * FEAT + c] = s0;
  partials[(blk * 2 + 1) * FEAT + c] = s1;
}

__global__ __launch_bounds__(256) void pool_fc(const float* __restrict__ partials,
                                               const float* __restrict__ Wfc, const float* __restrict__ bfc,
                                               float* __restrict__ out) {
  __shared__ float pooled[BATCH][FEAT];
  int t = threadIdx.x;  // channel
  float s0 = 0.f, s1 = 0.f;
  for (int p = 0; p < PBLK; ++p) {
    s0 += partials[(p * 2 + 0) * FEAT + t];
    s1 += partials[(p * 2 + 1) * FEAT + t];
  }
  pooled[0][t] = s0 / (float)NNODES;
  pooled[1][t] = s1 / (float)NNODES;
  __syncthreads();
  if (t < BATCH * OOUT) {
    int b = t >> 6, o = t & 63;
    float acc = bfc[o];
    for (int c2 = 0; c2 < FEAT; ++c2)
      acc = fmaf(pooled[b][c2], Wfc[c2 * OOUT + o], acc);
    out[b * OOUT + o] = acc;
  }
}

extern "C" void kernel_launch(void* const* d_in, const int* in_sizes, int n_in,
                              void* d_out, int out_size, void* d_ws, size_t ws_size,
                              hipStream_t stream) {
  const float* x    = (const float*)d_in[0];
  const float* W1   = (const float*)d_in[1];
  const float* b1   = (const float*)d_in[2];
  const float* W2   = (const float*)d_in[3];
  const float* b2   = (const float*)d_in[4];
  const float* Wfc  = (const float*)d_in[5];
  const float* bfc  = (const float*)d_in[6];
  const int*   eraw = (const int*)d_in[7];
  int E = in_sizes[7] / 2;
  float* out = (float*)d_out;

  char* ws = (char*)d_ws;
  size_t off = 0;
  auto alloc = [&](size_t elems) -> void* {   // elems in 4-byte units
    void* p = ws + off * 4;
    off += (elems + 3) & ~(size_t)3;          // keep 16B alignment
    return p;
  };
  int*   flag      = (int*)alloc(4);
  int*   s32       = (int*)alloc(E);
  int*   d32      = (int*)alloc(E);
  int*   cnt       = (int*)alloc(NNODES);
  float* dinv      = (float*)alloc(NNODES);
  int*   row_start = (int*)alloc(NNODES + 1);
  int*   fill      = (int*)alloc(NNODES);
  int*   csr_src   = (int*)alloc(E);
  float* csr_norm  = (float*)alloc(E);
  unsigned short* w1hi = (unsigned short*)alloc(65536 / 2);
  unsigned short* w1lo = (unsigned short*)alloc(65536 / 2);
  unsigned short* w2hi = (unsigned short*)alloc(65536 / 2);
  unsigned short* w2lo = (unsigned short*)alloc(65536 / 2);
  unsigned int*   h8   = (unsigned int*)alloc((size_t)MPAD * 64);            // fp8 GEMM out (padded)
  unsigned short* a1   = (unsigned short*)alloc((size_t)MROWS * FEAT / 2);   // agg out, bf16
  float* partials  = (float*)alloc((size_t)PBLK * BATCH * FEAT);

  int eg = (E + 255) / 256;
  detect_zero_kernel<<<1, 256, 0, stream>>>(eraw, flag, cnt, fill, E);
  convert_count_kernel<<<eg, 256, 0, stream>>>(eraw, flag, s32, d32, cnt, E);
  scan_dinv_kernel<<<1, 1024, 0, stream>>>(cnt, row_start, dinv, NNODES);
  scatter_kernel<<<eg, 256, 0, stream>>>(s32, d32, row_start, fill, dinv, csr_src, csr_norm, E);
  wprep_kernel<<<512, 256, 0, stream>>>(W1, W2, w1hi, w1lo, w2hi, w2lo);

  dim3 ggrid(MPAD / 128, 2);
  gemm_mfma<1><<<ggrid, 256, 0, stream>>>(x, w1hi, w1lo, h8);
  agg_kernel<<<NNODES, 128, 0, stream>>>((const uint4*)h8, row_start, csr_src, csr_norm, dinv, b1, a1);
  gemm_mfma<0><<<ggrid, 256, 0, stream>>>(a1, w2hi, w2lo, h8);
  agg_kernel<<<NNODES, 128, 0, stream>>>((const uint4*)h8, row_start, csr_src, csr_norm, dinv, b2, a1);
  pool_partial<<<PBLK, 256, 0, stream>>>(a1, partials);
  pool_fc<<<1, 256, 0, stream>>>(partials, Wfc, bfc, out);
}